// Round 10
// baseline (231.208 us; speedup 1.0000x reference)
//
#include <hip/hip_runtime.h>

// inputs: [M=4096, N=16384] fp32 logits; targets: [M] int32; k = int(0.01*(N-1)) = 163
#define M        4096
#define N        16384
#define K_SEL    163
#define DELTA_W  5.0f
#define NT       256
#define GRIDA    2048          // kernel A grid: 8 blocks/CU
#define ITERS    32            // (M*N/4) / (GRIDA*NT)
#define CAPW     512           // per-row LDS candidate cap (mean 372, sd 19; 7.4 sigma)
#define SCALE    4096.0f       // fixed-point for hard-negative sum (order-independent)
#define GSCALE   1048576.0     // 2^20 fixed-point for the global row-loss sum
#define THRESH   2.0f          // E[count(x>=2)] = 373 per row; 11 sigma above K_SEL

typedef float vfloat4 __attribute__((ext_vector_type(4)));

// Order-preserving float<->uint32 key (ascending float <-> ascending key)
__device__ __forceinline__ unsigned f2key(float x) {
    unsigned u = __float_as_uint(x);
    return u ^ ((unsigned)((int)u >> 31) | 0x80000000u);
}
__device__ __forceinline__ float key2f(unsigned k) {
    unsigned u = k ^ (~(unsigned)((int)k >> 31) | 0x80000000u);
    return __uint_as_float(u);
}
__device__ __forceinline__ void wave_lgkm_wait() {
    asm volatile("s_waitcnt lgkmcnt(0)" ::: "memory");
}

// ---------- Kernel A: PURE COPY SHAPE. load float4 -> 4 cmp -> store 1 byte. ----------
// No ballot, no exec divergence, no LDS, no atomics. Launched 3x this round as a
// timing probe (idempotent): total = 3*A + B + fin pins A's true duration.
__global__ __launch_bounds__(NT) void stream_mask(
    const float* __restrict__ inp, unsigned char* __restrict__ mask,
    unsigned long long* __restrict__ acc)
{
    const int tid = threadIdx.x;
    if (blockIdx.x == 0 && tid == 0) *acc = 0ull;   // runs before B: safe zero

    const vfloat4* p4 = reinterpret_cast<const vfloat4*>(inp);
    const unsigned gbase = blockIdx.x * NT + tid;

    #pragma unroll 8
    for (int it = 0; it < ITERS; ++it) {
        const unsigned g = (unsigned)it * (GRIDA * NT) + gbase;   // float4 index
        vfloat4 v = p4[g];
        unsigned nib = (v[0] >= THRESH ? 1u : 0u)
                     | (v[1] >= THRESH ? 2u : 0u)
                     | (v[2] >= THRESH ? 4u : 0u)
                     | (v[3] >= THRESH ? 8u : 0u);
        mask[g] = (unsigned char)nib;                // 64 B/wave, coalesced
    }
}

// ---------- Kernel B: wave-per-row. Byte-mask -> gather -> radix select -> loss. ----------
__global__ __launch_bounds__(NT) void select_and_loss(
    const float* __restrict__ inp, const int* __restrict__ tgt,
    const unsigned char* __restrict__ mask,
    unsigned long long* __restrict__ acc)
{
    __shared__ unsigned hist_all[4][256];   // wave-private 1 KiB
    __shared__ unsigned list_all[4][CAPW];  // wave-private 2 KiB
    const int lane = threadIdx.x & 63;
    const int wv   = threadIdx.x >> 6;
    const int row  = blockIdx.x * 4 + wv;
    unsigned* hist = hist_all[wv];
    unsigned* list = list_all[wv];
    const float* rp = inp + (size_t)row * N;
    const int target = tgt[row];

    // lane owns 256 elements = 64 mask bytes = 16 u32 words (low nibbles hold bits)
    const uint4* mrow = reinterpret_cast<const uint4*>(mask + (size_t)row * (N / 4));
    unsigned w16[16];
    {
        uint4 a = mrow[lane * 4 + 0], b = mrow[lane * 4 + 1],
              c = mrow[lane * 4 + 2], d = mrow[lane * 4 + 3];
        w16[0]=a.x; w16[1]=a.y; w16[2]=a.z;  w16[3]=a.w;
        w16[4]=b.x; w16[5]=b.y; w16[6]=b.z;  w16[7]=b.w;
        w16[8]=c.x; w16[9]=c.y; w16[10]=c.z; w16[11]=c.w;
        w16[12]=d.x;w16[13]=d.y;w16[14]=d.z; w16[15]=d.w;
    }
    // clear the positive's bit (static indexing only -> stays in registers)
    {
        const bool mine = ((target >> 8) == lane);
        const unsigned tw = (((unsigned)target >> 2) & 63u) >> 2;        // word 0..15
        const unsigned tb = ((((unsigned)target >> 2) & 3u) << 3) + ((unsigned)target & 3u);
        #pragma unroll
        for (int i = 0; i < 16; ++i)
            if (mine && ((unsigned)i == tw)) w16[i] &= ~(1u << tb);
    }

    unsigned myc = 0;
    #pragma unroll
    for (int i = 0; i < 16; ++i) myc += (unsigned)__popc(w16[i]);

    unsigned inc = myc;                      // inclusive scan over lanes
    #pragma unroll
    for (int off = 1; off < 64; off <<= 1) {
        unsigned t = __shfl_up(inc, off);
        if (lane >= off) inc += t;
    }
    const unsigned C   = __shfl(inc, 63);    // exact row candidate count
    const unsigned pre = inc - myc;          // deterministic slot base

    unsigned prefix = 0u, kr = K_SEL;
    float loss = 0.0f;
    bool have = false;

    if (C >= K_SEL && C <= CAPW) {
        // gather candidates into wave-private LDS list at fixed positions
        unsigned pos = pre;
        #pragma unroll
        for (int i = 0; i < 16; ++i) {
            unsigned m = w16[i];
            while (m) {
                const int p = __builtin_ctz(m); m &= m - 1;
                const int idx = lane * 256 + (i * 4 + (p >> 3)) * 4 + (p & 7);
                list[pos++] = f2key(rp[idx]);
            }
        }
        wave_lgkm_wait();

        unsigned keys[8];
        #pragma unroll
        for (int it = 0; it < 8; ++it) {
            const unsigned i = lane + it * 64u;
            keys[it] = (i < C) ? list[i] : 0u;     // pad with min-key
        }
        for (int pass = 0; pass < 4; ++pass) {
            *reinterpret_cast<uint4*>(&hist[lane * 4]) = make_uint4(0, 0, 0, 0);
            wave_lgkm_wait();
            const int shift = 24 - 8 * pass;
            #pragma unroll
            for (int it = 0; it < 8; ++it) {
                unsigned k = keys[it];
                bool mm = (lane + it * 64u < C) &&
                          (pass == 0 || (k >> (shift + 8)) == prefix);
                if (mm) atomicAdd(&hist[(k >> shift) & 0xFFu], 1u);
            }
            wave_lgkm_wait();
            uint4 h = *reinterpret_cast<const uint4*>(&hist[lane * 4]);
            unsigned hb[4] = {h.x, h.y, h.z, h.w};
            unsigned s_local = hb[0] + hb[1] + hb[2] + hb[3];
            unsigned suf = s_local;                // suffix-scan over lanes
            #pragma unroll
            for (int off = 1; off < 64; off <<= 1) {
                unsigned o = __shfl_down(suf, off);
                suf += (lane + off < 64) ? o : 0u;
            }
            unsigned acc_above = suf - s_local;
            int foundc = -1; unsigned f_abv = 0;
            #pragma unroll
            for (int c = 3; c >= 0; --c) {
                unsigned S = acc_above + hb[c];
                if (acc_above < kr && S >= kr) { foundc = c; f_abv = acc_above; }
                acc_above = S;
            }
            bool win = (foundc >= 0);
            unsigned long long bal = __ballot(win);
            int wl = __ffsll((long long)bal) - 1;
            unsigned np = win ? ((prefix << 8) | (unsigned)(lane * 4 + foundc)) : 0u;
            unsigned nk = win ? (kr - f_abv) : 0u;
            prefix = __shfl(np, wl);
            kr     = __shfl(nk, wl);
        }
        const unsigned tkey = prefix, krem = kr;

        int facc = 0;                              // fixed-point, order-independent
        #pragma unroll
        for (int it = 0; it < 8; ++it) {
            unsigned k = keys[it];
            if ((lane + it * 64u) < C && k > tkey) {
                float ww = key2f(k) + 1.0f;
                facc += (int)(ww * ww * SCALE + 0.5f);
            }
        }
        #pragma unroll
        for (int off = 32; off > 0; off >>= 1) facc += __shfl_down(facc, off);
        if (lane == 0) {
            float tv    = key2f(tkey) + 1.0f;
            float total = (float)facc * (1.0f / SCALE) + (float)krem * tv * tv;
            float pd    = rp[target] - 1.0f;
            loss = DELTA_W * pd * pd + total * (1.0f / (float)K_SEL);
            have = true;
        }
    } else {
        // fallback: exact full-row radix (never taken for Gaussian bench data)
        for (int pass = 0; pass < 4; ++pass) {
            *reinterpret_cast<uint4*>(&hist[lane * 4]) = make_uint4(0, 0, 0, 0);
            wave_lgkm_wait();
            const int shift = 24 - 8 * pass;
            for (int it = 0; it < N / 64; ++it) {
                int i = lane + it * 64;
                unsigned k = f2key(rp[i]);
                if (i == target) k = 0u;
                bool mm = (pass == 0) || ((k >> (shift + 8)) == prefix);
                if (mm) atomicAdd(&hist[(k >> shift) & 0xFFu], 1u);
            }
            wave_lgkm_wait();
            uint4 h = *reinterpret_cast<const uint4*>(&hist[lane * 4]);
            unsigned hb[4] = {h.x, h.y, h.z, h.w};
            unsigned s_local = hb[0] + hb[1] + hb[2] + hb[3];
            unsigned suf = s_local;
            #pragma unroll
            for (int off = 1; off < 64; off <<= 1) {
                unsigned o = __shfl_down(suf, off);
                suf += (lane + off < 64) ? o : 0u;
            }
            unsigned acc_above = suf - s_local;
            int foundc = -1; unsigned f_abv = 0;
            #pragma unroll
            for (int c = 3; c >= 0; --c) {
                unsigned S = acc_above + hb[c];
                if (acc_above < kr && S >= kr) { foundc = c; f_abv = acc_above; }
                acc_above = S;
            }
            bool win = (foundc >= 0);
            unsigned long long bal = __ballot(win);
            int wl = __ffsll((long long)bal) - 1;
            unsigned np = win ? ((prefix << 8) | (unsigned)(lane * 4 + foundc)) : 0u;
            unsigned nk = win ? (kr - f_abv) : 0u;
            prefix = __shfl(np, wl);
            kr     = __shfl(nk, wl);
        }
        const unsigned tkey = prefix, krem = kr;

        int facc = 0;
        for (int it = 0; it < N / 64; ++it) {
            int i = lane + it * 64;
            unsigned k = f2key(rp[i]);
            if (i == target) k = 0u;
            if (k > tkey) { float ww = key2f(k) + 1.0f; facc += (int)(ww * ww * SCALE + 0.5f); }
        }
        #pragma unroll
        for (int off = 32; off > 0; off >>= 1) facc += __shfl_down(facc, off);
        if (lane == 0) {
            float tv    = key2f(tkey) + 1.0f;
            float total = (float)facc * (1.0f / SCALE) + (float)krem * tv * tv;
            float pd    = rp[target] - 1.0f;
            loss = DELTA_W * pd * pd + total * (1.0f / (float)K_SEL);
            have = true;
        }
    }

    // deterministic global mean: 2^20 fixed-point integer accumulate (loss >= 0)
    if (have) {
        unsigned long long q = (unsigned long long)((double)loss * GSCALE + 0.5);
        atomicAdd(acc, q);
    }
}

__global__ void finalize(const unsigned long long* __restrict__ acc,
                         float* __restrict__ out)
{
    if (threadIdx.x == 0)
        out[0] = (float)((double)(*acc) / (GSCALE * (double)M));
}

extern "C" void kernel_launch(void* const* d_in, const int* in_sizes, int n_in,
                              void* d_out, int out_size, void* d_ws, size_t ws_size,
                              hipStream_t stream) {
    const float* inp = (const float*)d_in[0];
    const int*   tgt = (const int*)d_in[1];
    float* out = (float*)d_out;

    // ws layout: byte mask (16 MiB) | acc (8 B)
    unsigned char* mask = (unsigned char*)d_ws;
    unsigned long long* acc =
        (unsigned long long*)((char*)d_ws + (size_t)M * (N / 4));

    // TIMING PROBE this round: A launched 3x (idempotent).
    // total = 3*A + B + fin; with R9's 124 = A_old + B + fin this pins A.
    stream_mask<<<GRIDA, NT, 0, stream>>>(inp, mask, acc);
    stream_mask<<<GRIDA, NT, 0, stream>>>(inp, mask, acc);
    stream_mask<<<GRIDA, NT, 0, stream>>>(inp, mask, acc);
    select_and_loss<<<M / 4, NT, 0, stream>>>(inp, tgt, mask, acc);
    finalize<<<1, 64, 0, stream>>>(acc, out);
}

// Round 11
// 137.855 us; speedup vs baseline: 1.6772x; 1.6772x over previous
//
#include <hip/hip_runtime.h>

// inputs: [M=4096, N=16384] fp32 logits; targets: [M] int32; k = int(0.01*(N-1)) = 163
#define M        4096
#define N        16384
#define K_SEL    163
#define DELTA_W  5.0f
#define NT       256
#define GRIDA    2048          // kernel A grid: 8 blocks/CU
#define ITERS    32            // (M*N/4) / (GRIDA*NT)
#define CAPW     512           // per-row candidate cap (mean 372, sd 19; 7.4 sigma)
#define SCALE    4096.0f       // fixed-point for hard-negative sum (order-independent)
#define THRESH   2.0f          // E[count(x>=2)] = 373 per row; 11 sigma above K_SEL

typedef float vfloat4 __attribute__((ext_vector_type(4)));

// Order-preserving float<->uint32 key (ascending float <-> ascending key)
__device__ __forceinline__ unsigned f2key(float x) {
    unsigned u = __float_as_uint(x);
    return u ^ ((unsigned)((int)u >> 31) | 0x80000000u);
}
__device__ __forceinline__ float key2f(unsigned k) {
    unsigned u = k ^ (~(unsigned)((int)k >> 31) | 0x80000000u);
    return __uint_as_float(u);
}
__device__ __forceinline__ void wave_lgkm_wait() {
    asm volatile("s_waitcnt lgkmcnt(0)" ::: "memory");
}

// ---------- Kernel A: pure copy shape (measured ~53 us, ~5.1 TB/s). ----------
__global__ __launch_bounds__(NT) void stream_mask(
    const float* __restrict__ inp, unsigned char* __restrict__ mask)
{
    const int tid = threadIdx.x;
    const vfloat4* p4 = reinterpret_cast<const vfloat4*>(inp);
    const unsigned gbase = blockIdx.x * NT + tid;

    #pragma unroll 8
    for (int it = 0; it < ITERS; ++it) {
        const unsigned g = (unsigned)it * (GRIDA * NT) + gbase;   // float4 index
        vfloat4 v = p4[g];
        unsigned nib = (v[0] >= THRESH ? 1u : 0u)
                     | (v[1] >= THRESH ? 2u : 0u)
                     | (v[2] >= THRESH ? 4u : 0u)
                     | (v[3] >= THRESH ? 8u : 0u);
        mask[g] = (unsigned char)nib;                // 64 B/wave, coalesced
    }
}

// ---------- Kernel B: wave-per-row. Address-phase gather (no per-load waits), ----------
// ---------- common-prefix-skipping radix select. Idempotent (row_loss).      ----------
__global__ __launch_bounds__(NT) void select_and_loss(
    const float* __restrict__ inp, const int* __restrict__ tgt,
    const unsigned char* __restrict__ mask,
    float* __restrict__ row_loss)
{
    __shared__ unsigned hist_all[4][256];   // wave-private 1 KiB
    __shared__ unsigned list_all[4][CAPW];  // wave-private 2 KiB (addresses)
    const int lane = threadIdx.x & 63;
    const int wv   = threadIdx.x >> 6;
    const int row  = blockIdx.x * 4 + wv;
    unsigned* hist = hist_all[wv];
    unsigned* list = list_all[wv];
    const float* rp = inp + (size_t)row * N;
    const int target = tgt[row];

    // lane owns 256 elements = 64 mask bytes = 16 u32 words (low nibbles hold bits)
    const uint4* mrow = reinterpret_cast<const uint4*>(mask + (size_t)row * (N / 4));
    unsigned w16[16];
    {
        uint4 a = mrow[lane * 4 + 0], b = mrow[lane * 4 + 1],
              c = mrow[lane * 4 + 2], d = mrow[lane * 4 + 3];
        w16[0]=a.x; w16[1]=a.y; w16[2]=a.z;  w16[3]=a.w;
        w16[4]=b.x; w16[5]=b.y; w16[6]=b.z;  w16[7]=b.w;
        w16[8]=c.x; w16[9]=c.y; w16[10]=c.z; w16[11]=c.w;
        w16[12]=d.x;w16[13]=d.y;w16[14]=d.z; w16[15]=d.w;
    }
    // clear the positive's bit (static indexing -> registers)
    {
        const bool mine = ((target >> 8) == lane);
        const unsigned tw = (((unsigned)target >> 2) & 63u) >> 2;
        const unsigned tb = ((((unsigned)target >> 2) & 3u) << 3) + ((unsigned)target & 3u);
        #pragma unroll
        for (int i = 0; i < 16; ++i)
            if (mine && ((unsigned)i == tw)) w16[i] &= ~(1u << tb);
    }

    unsigned myc = 0;
    #pragma unroll
    for (int i = 0; i < 16; ++i) myc += (unsigned)__popc(w16[i]);

    unsigned inc = myc;                      // inclusive scan over lanes
    #pragma unroll
    for (int off = 1; off < 64; off <<= 1) {
        unsigned t = __shfl_up(inc, off);
        if (lane >= off) inc += t;
    }
    const unsigned C   = __shfl(inc, 63);    // exact row candidate count
    const unsigned pre = inc - myc;          // deterministic slot base

    float loss = 0.0f;
    bool have = false;

    if (C >= K_SEL && C <= CAPW) {
        // ---- phase 1: write candidate ADDRESSES to LDS (VALU+DS only, no waits) ----
        unsigned pos = pre;
        #pragma unroll
        for (int i = 0; i < 16; ++i) {
            unsigned m = w16[i];
            while (m) {
                const int p = __builtin_ctz(m); m &= m - 1;
                const unsigned idx = (unsigned)(lane * 256 + (i * 4 + (p >> 3)) * 4 + (p & 3));
                list[pos++] = idx;
            }
        }
        wave_lgkm_wait();

        // ---- phase 2: 8 independent scattered loads, single wait ----
        float vals[8];
        #pragma unroll
        for (int it = 0; it < 8; ++it) {
            const unsigned i = lane + it * 64u;
            const unsigned a = (i < C) ? list[i] : 0u;
            vals[it] = rp[a];
        }
        unsigned keys[8];
        #pragma unroll
        for (int it = 0; it < 8; ++it) {
            const unsigned i = lane + it * 64u;
            keys[it] = (i < C) ? f2key(vals[it]) : 0u;
        }

        // ---- common-prefix detection: skip degenerate leading radix passes ----
        unsigned mn = 0xFFFFFFFFu, mx = 0u;
        #pragma unroll
        for (int it = 0; it < 8; ++it) {
            const unsigned i = lane + it * 64u;
            if (i < C) { mn = min(mn, keys[it]); mx = max(mx, keys[it]); }
        }
        #pragma unroll
        for (int off = 32; off > 0; off >>= 1) {
            mn = min(mn, (unsigned)__shfl_xor((int)mn, off));
            mx = max(mx, (unsigned)__shfl_xor((int)mx, off));
        }
        const unsigned diff = mn ^ mx;
        const int b0 = (diff == 0u) ? 3 : (__clz(diff) >> 3);   // first differing byte
        unsigned prefix = (b0 == 0) ? 0u : (mn >> (32 - 8 * b0));
        unsigned kr = K_SEL;

        for (int pass = b0; pass < 4; ++pass) {
            *reinterpret_cast<uint4*>(&hist[lane * 4]) = make_uint4(0, 0, 0, 0);
            wave_lgkm_wait();
            const int shift = 24 - 8 * pass;
            #pragma unroll
            for (int it = 0; it < 8; ++it) {
                unsigned k = keys[it];
                bool mm = (lane + it * 64u < C) &&
                          (pass == 0 || (k >> (shift + 8)) == prefix);
                if (mm) atomicAdd(&hist[(k >> shift) & 0xFFu], 1u);
            }
            wave_lgkm_wait();
            uint4 h = *reinterpret_cast<const uint4*>(&hist[lane * 4]);
            unsigned hb[4] = {h.x, h.y, h.z, h.w};
            unsigned s_local = hb[0] + hb[1] + hb[2] + hb[3];
            unsigned suf = s_local;                // suffix-scan over lanes
            #pragma unroll
            for (int off = 1; off < 64; off <<= 1) {
                unsigned o = __shfl_down(suf, off);
                suf += (lane + off < 64) ? o : 0u;
            }
            unsigned acc_above = suf - s_local;
            int foundc = -1; unsigned f_abv = 0;
            #pragma unroll
            for (int c = 3; c >= 0; --c) {
                unsigned S = acc_above + hb[c];
                if (acc_above < kr && S >= kr) { foundc = c; f_abv = acc_above; }
                acc_above = S;
            }
            bool win = (foundc >= 0);
            unsigned long long bal = __ballot(win);
            int wl = __ffsll((long long)bal) - 1;
            unsigned np = win ? ((prefix << 8) | (unsigned)(lane * 4 + foundc)) : 0u;
            unsigned nk = win ? (kr - f_abv) : 0u;
            prefix = __shfl(np, wl);
            kr     = __shfl(nk, wl);
        }
        const unsigned tkey = prefix, krem = kr;

        int facc = 0;                              // fixed-point, order-independent
        #pragma unroll
        for (int it = 0; it < 8; ++it) {
            unsigned k = keys[it];
            if ((lane + it * 64u) < C && k > tkey) {
                float ww = key2f(k) + 1.0f;
                facc += (int)(ww * ww * SCALE + 0.5f);
            }
        }
        #pragma unroll
        for (int off = 32; off > 0; off >>= 1) facc += __shfl_down(facc, off);
        if (lane == 0) {
            float tv    = key2f(tkey) + 1.0f;
            float total = (float)facc * (1.0f / SCALE) + (float)krem * tv * tv;
            float pd    = rp[target] - 1.0f;
            loss = DELTA_W * pd * pd + total * (1.0f / (float)K_SEL);
            have = true;
        }
    } else {
        // fallback: exact full-row radix (never taken for Gaussian bench data)
        unsigned prefix = 0u, kr = K_SEL;
        for (int pass = 0; pass < 4; ++pass) {
            *reinterpret_cast<uint4*>(&hist[lane * 4]) = make_uint4(0, 0, 0, 0);
            wave_lgkm_wait();
            const int shift = 24 - 8 * pass;
            for (int it = 0; it < N / 64; ++it) {
                int i = lane + it * 64;
                unsigned k = f2key(rp[i]);
                if (i == target) k = 0u;
                bool mm = (pass == 0) || ((k >> (shift + 8)) == prefix);
                if (mm) atomicAdd(&hist[(k >> shift) & 0xFFu], 1u);
            }
            wave_lgkm_wait();
            uint4 h = *reinterpret_cast<const uint4*>(&hist[lane * 4]);
            unsigned hb[4] = {h.x, h.y, h.z, h.w};
            unsigned s_local = hb[0] + hb[1] + hb[2] + hb[3];
            unsigned suf = s_local;
            #pragma unroll
            for (int off = 1; off < 64; off <<= 1) {
                unsigned o = __shfl_down(suf, off);
                suf += (lane + off < 64) ? o : 0u;
            }
            unsigned acc_above = suf - s_local;
            int foundc = -1; unsigned f_abv = 0;
            #pragma unroll
            for (int c = 3; c >= 0; --c) {
                unsigned S = acc_above + hb[c];
                if (acc_above < kr && S >= kr) { foundc = c; f_abv = acc_above; }
                acc_above = S;
            }
            bool win = (foundc >= 0);
            unsigned long long bal = __ballot(win);
            int wl = __ffsll((long long)bal) - 1;
            unsigned np = win ? ((prefix << 8) | (unsigned)(lane * 4 + foundc)) : 0u;
            unsigned nk = win ? (kr - f_abv) : 0u;
            prefix = __shfl(np, wl);
            kr     = __shfl(nk, wl);
        }
        const unsigned tkey = prefix, krem = kr;

        int facc = 0;
        for (int it = 0; it < N / 64; ++it) {
            int i = lane + it * 64;
            unsigned k = f2key(rp[i]);
            if (i == target) k = 0u;
            if (k > tkey) { float ww = key2f(k) + 1.0f; facc += (int)(ww * ww * SCALE + 0.5f); }
        }
        #pragma unroll
        for (int off = 32; off > 0; off >>= 1) facc += __shfl_down(facc, off);
        if (lane == 0) {
            float tv    = key2f(tkey) + 1.0f;
            float total = (float)facc * (1.0f / SCALE) + (float)krem * tv * tv;
            float pd    = rp[target] - 1.0f;
            loss = DELTA_W * pd * pd + total * (1.0f / (float)K_SEL);
            have = true;
        }
    }

    if (have) row_loss[row] = loss;   // idempotent: B can launch multiple times
}

__global__ __launch_bounds__(256) void final_reduce(
    const float* __restrict__ rl, float* __restrict__ out)
{
    int tid = threadIdx.x;
    float s = 0.0f;
    for (int i = tid; i < M; i += 256) s += rl[i];   // fixed order -> deterministic
    __shared__ float wp[4];
    int lane = tid & 63, wv = tid >> 6;
    #pragma unroll
    for (int off = 32; off > 0; off >>= 1) s += __shfl_down(s, off);
    if (lane == 0) wp[wv] = s;
    __syncthreads();
    if (tid == 0) out[0] = (wp[0] + wp[1] + wp[2] + wp[3]) / (float)M;
}

extern "C" void kernel_launch(void* const* d_in, const int* in_sizes, int n_in,
                              void* d_out, int out_size, void* d_ws, size_t ws_size,
                              hipStream_t stream) {
    const float* inp = (const float*)d_in[0];
    const int*   tgt = (const int*)d_in[1];
    float* out = (float*)d_out;

    // ws layout: byte mask (16 MiB) | row_loss (16 KiB)
    unsigned char* mask = (unsigned char*)d_ws;
    float* row_loss = (float*)((char*)d_ws + (size_t)M * (N / 4));

    stream_mask<<<GRIDA, NT, 0, stream>>>(inp, mask);
    // PROBE: B launched 3x (idempotent) to pin B's true cost within-round.
    select_and_loss<<<M / 4, NT, 0, stream>>>(inp, tgt, mask, row_loss);
    select_and_loss<<<M / 4, NT, 0, stream>>>(inp, tgt, mask, row_loss);
    select_and_loss<<<M / 4, NT, 0, stream>>>(inp, tgt, mask, row_loss);
    final_reduce<<<1, 256, 0, stream>>>(row_loss, out);
}

// Round 12
// 72.240 us; speedup vs baseline: 3.2005x; 1.9083x over previous
//
#include <hip/hip_runtime.h>

// inputs: [M=4096, N=16384] fp32 logits; targets: [M] int32; k = int(0.01*(N-1)) = 163
#define M        4096
#define N        16384
#define K_SEL    163
#define DELTA_W  5.0f
#define NT       256
#define CAPW     512           // per-row candidate cap (mean 372, sd 19; 7.4 sigma)
#define SCALE    4096.0f       // fixed-point for hard-negative sum (order-independent)
#define THRESH   2.0f          // E[count(x>=2)] = 373 per row; 11 sigma above K_SEL

typedef float vfloat4 __attribute__((ext_vector_type(4)));

// Order-preserving float<->uint32 key (ascending float <-> ascending key)
__device__ __forceinline__ unsigned f2key(float x) {
    unsigned u = __float_as_uint(x);
    return u ^ ((unsigned)((int)u >> 31) | 0x80000000u);
}
__device__ __forceinline__ float key2f(unsigned k) {
    unsigned u = k ^ (~(unsigned)((int)k >> 31) | 0x80000000u);
    return __uint_as_float(u);
}
__device__ __forceinline__ void wave_lgkm_wait() {
    asm volatile("s_waitcnt lgkmcnt(0)" ::: "memory");
}

// ---------- Fused kernel: wave-per-row stream + select. ----------
// Streaming loop is copy-shape (R9/R10-proven): load float4 -> 4 cmp -> 4 ballot ->
// lane==it latch (cndmask). Mask lives in 4 VGPRs/lane; no LDS/stores in the loop.
__global__ __launch_bounds__(NT, 4) void fused_row_loss(
    const float* __restrict__ inp, const int* __restrict__ tgt,
    float* __restrict__ row_loss)
{
    __shared__ unsigned hist_all[4][256];   // wave-private 1 KiB
    __shared__ unsigned list_all[4][CAPW];  // wave-private 2 KiB (addresses)
    const int lane = threadIdx.x & 63;
    const int wv   = threadIdx.x >> 6;
    const int row  = blockIdx.x * 4 + wv;
    unsigned* hist = hist_all[wv];
    unsigned* list = list_all[wv];
    const float* rp = inp + (size_t)row * N;
    const vfloat4* rp4 = reinterpret_cast<const vfloat4*>(rp);
    const int target = tgt[row];

    // ---- Phase 1: stream own row; lane latches ballot words for iter==lane ----
    // Element mapping: iter it, ballot j, bit p  <->  element it*256 + 4p + j.
    unsigned long long w0 = 0, w1 = 0, w2 = 0, w3 = 0;
    #pragma unroll
    for (int bb = 0; bb < 4; ++bb) {
        vfloat4 v[16];                       // 16 loads in flight (64 VGPR)
        #pragma unroll
        for (int u = 0; u < 16; ++u) v[u] = rp4[(bb * 16 + u) * 64 + lane];
        #pragma unroll
        for (int u = 0; u < 16; ++u) {
            const int it = bb * 16 + u;      // compile-time constant per instance
            unsigned long long b0 = __ballot(v[u][0] >= THRESH);
            unsigned long long b1 = __ballot(v[u][1] >= THRESH);
            unsigned long long b2 = __ballot(v[u][2] >= THRESH);
            unsigned long long b3 = __ballot(v[u][3] >= THRESH);
            if (lane == it) { w0 = b0; w1 = b1; w2 = b2; w3 = b3; }
        }
    }

    // clear the positive's bit: element t -> chunk t>>8, j = t&3, bit p = (t&255)>>2
    if ((target >> 8) == lane) {
        const int j = target & 3;
        const unsigned long long bit = 1ull << ((target & 255) >> 2);
        if (j == 0) w0 &= ~bit;
        if (j == 1) w1 &= ~bit;
        if (j == 2) w2 &= ~bit;
        if (j == 3) w3 &= ~bit;
    }

    const unsigned myc = (unsigned)(__popcll(w0) + __popcll(w1)
                                  + __popcll(w2) + __popcll(w3));
    unsigned inc = myc;                      // inclusive scan over lanes
    #pragma unroll
    for (int off = 1; off < 64; off <<= 1) {
        unsigned t = __shfl_up(inc, off);
        if (lane >= off) inc += t;
    }
    const unsigned C   = __shfl(inc, 63);    // exact row candidate count
    const unsigned pre = inc - myc;          // deterministic slot base

    float loss = 0.0f;
    bool have = false;

    if (C >= K_SEL && C <= CAPW) {
        // ---- address phase: decode bits -> LDS list (VALU+DS only) ----
        unsigned pos = pre;
        #pragma unroll
        for (int j = 0; j < 4; ++j) {
            unsigned long long m = (j == 0) ? w0 : (j == 1) ? w1 : (j == 2) ? w2 : w3;
            while (m) {
                const int p = __builtin_ctzll(m); m &= m - 1;
                list[pos++] = (unsigned)(lane * 256 + 4 * p + j);
            }
        }
        wave_lgkm_wait();

        // ---- gather: 8 independent scattered loads (row L2/L3-hot), one wait ----
        float vals[8];
        #pragma unroll
        for (int it = 0; it < 8; ++it) {
            const unsigned i = lane + it * 64u;
            const unsigned a = (i < C) ? list[i] : 0u;
            vals[it] = rp[a];
        }
        unsigned keys[8];
        #pragma unroll
        for (int it = 0; it < 8; ++it) {
            const unsigned i = lane + it * 64u;
            keys[it] = (i < C) ? f2key(vals[it]) : 0u;
        }

        // ---- common-prefix detection: skip degenerate leading radix passes ----
        unsigned mn = 0xFFFFFFFFu, mx = 0u;
        #pragma unroll
        for (int it = 0; it < 8; ++it) {
            const unsigned i = lane + it * 64u;
            if (i < C) { mn = min(mn, keys[it]); mx = max(mx, keys[it]); }
        }
        #pragma unroll
        for (int off = 32; off > 0; off >>= 1) {
            mn = min(mn, (unsigned)__shfl_xor((int)mn, off));
            mx = max(mx, (unsigned)__shfl_xor((int)mx, off));
        }
        const unsigned diff = mn ^ mx;
        const int b0i = (diff == 0u) ? 3 : (__clz(diff) >> 3);   // first differing byte
        unsigned prefix = (b0i == 0) ? 0u : (mn >> (32 - 8 * b0i));
        unsigned kr = K_SEL;

        for (int pass = b0i; pass < 4; ++pass) {
            *reinterpret_cast<uint4*>(&hist[lane * 4]) = make_uint4(0, 0, 0, 0);
            wave_lgkm_wait();
            const int shift = 24 - 8 * pass;
            #pragma unroll
            for (int it = 0; it < 8; ++it) {
                unsigned k = keys[it];
                bool mm = (lane + it * 64u < C) &&
                          (pass == 0 || (k >> (shift + 8)) == prefix);
                if (mm) atomicAdd(&hist[(k >> shift) & 0xFFu], 1u);
            }
            wave_lgkm_wait();
            uint4 h = *reinterpret_cast<const uint4*>(&hist[lane * 4]);
            unsigned hb[4] = {h.x, h.y, h.z, h.w};
            unsigned s_local = hb[0] + hb[1] + hb[2] + hb[3];
            unsigned suf = s_local;                // suffix-scan over lanes
            #pragma unroll
            for (int off = 1; off < 64; off <<= 1) {
                unsigned o = __shfl_down(suf, off);
                suf += (lane + off < 64) ? o : 0u;
            }
            unsigned acc_above = suf - s_local;
            int foundc = -1; unsigned f_abv = 0;
            #pragma unroll
            for (int c = 3; c >= 0; --c) {
                unsigned S = acc_above + hb[c];
                if (acc_above < kr && S >= kr) { foundc = c; f_abv = acc_above; }
                acc_above = S;
            }
            bool win = (foundc >= 0);
            unsigned long long bal = __ballot(win);
            int wl = __ffsll((long long)bal) - 1;
            unsigned np = win ? ((prefix << 8) | (unsigned)(lane * 4 + foundc)) : 0u;
            unsigned nk = win ? (kr - f_abv) : 0u;
            prefix = __shfl(np, wl);
            kr     = __shfl(nk, wl);
        }
        const unsigned tkey = prefix, krem = kr;

        int facc = 0;                              // fixed-point, order-independent
        #pragma unroll
        for (int it = 0; it < 8; ++it) {
            unsigned k = keys[it];
            if ((lane + it * 64u) < C && k > tkey) {
                float ww = key2f(k) + 1.0f;
                facc += (int)(ww * ww * SCALE + 0.5f);
            }
        }
        #pragma unroll
        for (int off = 32; off > 0; off >>= 1) facc += __shfl_down(facc, off);
        if (lane == 0) {
            float tv    = key2f(tkey) + 1.0f;
            float total = (float)facc * (1.0f / SCALE) + (float)krem * tv * tv;
            float pd    = rp[target] - 1.0f;
            loss = DELTA_W * pd * pd + total * (1.0f / (float)K_SEL);
            have = true;
        }
    } else {
        // ---- fallback: exact full-row radix (never taken for Gaussian bench data) ----
        unsigned prefix = 0u, kr = K_SEL;
        for (int pass = 0; pass < 4; ++pass) {
            *reinterpret_cast<uint4*>(&hist[lane * 4]) = make_uint4(0, 0, 0, 0);
            wave_lgkm_wait();
            const int shift = 24 - 8 * pass;
            for (int it = 0; it < N / 64; ++it) {
                int i = lane + it * 64;
                unsigned k = f2key(rp[i]);
                if (i == target) k = 0u;
                bool mm = (pass == 0) || ((k >> (shift + 8)) == prefix);
                if (mm) atomicAdd(&hist[(k >> shift) & 0xFFu], 1u);
            }
            wave_lgkm_wait();
            uint4 h = *reinterpret_cast<const uint4*>(&hist[lane * 4]);
            unsigned hb[4] = {h.x, h.y, h.z, h.w};
            unsigned s_local = hb[0] + hb[1] + hb[2] + hb[3];
            unsigned suf = s_local;
            #pragma unroll
            for (int off = 1; off < 64; off <<= 1) {
                unsigned o = __shfl_down(suf, off);
                suf += (lane + off < 64) ? o : 0u;
            }
            unsigned acc_above = suf - s_local;
            int foundc = -1; unsigned f_abv = 0;
            #pragma unroll
            for (int c = 3; c >= 0; --c) {
                unsigned S = acc_above + hb[c];
                if (acc_above < kr && S >= kr) { foundc = c; f_abv = acc_above; }
                acc_above = S;
            }
            bool win = (foundc >= 0);
            unsigned long long bal = __ballot(win);
            int wl = __ffsll((long long)bal) - 1;
            unsigned np = win ? ((prefix << 8) | (unsigned)(lane * 4 + foundc)) : 0u;
            unsigned nk = win ? (kr - f_abv) : 0u;
            prefix = __shfl(np, wl);
            kr     = __shfl(nk, wl);
        }
        const unsigned tkey = prefix, krem = kr;

        int facc = 0;
        for (int it = 0; it < N / 64; ++it) {
            int i = lane + it * 64;
            unsigned k = f2key(rp[i]);
            if (i == target) k = 0u;
            if (k > tkey) { float ww = key2f(k) + 1.0f; facc += (int)(ww * ww * SCALE + 0.5f); }
        }
        #pragma unroll
        for (int off = 32; off > 0; off >>= 1) facc += __shfl_down(facc, off);
        if (lane == 0) {
            float tv    = key2f(tkey) + 1.0f;
            float total = (float)facc * (1.0f / SCALE) + (float)krem * tv * tv;
            float pd    = rp[target] - 1.0f;
            loss = DELTA_W * pd * pd + total * (1.0f / (float)K_SEL);
            have = true;
        }
    }

    if (have) row_loss[row] = loss;
}

__global__ __launch_bounds__(256) void final_reduce(
    const float* __restrict__ rl, float* __restrict__ out)
{
    int tid = threadIdx.x;
    float s = 0.0f;
    for (int i = tid; i < M; i += 256) s += rl[i];   // fixed order -> deterministic
    __shared__ float wp[4];
    int lane = tid & 63, wv = tid >> 6;
    #pragma unroll
    for (int off = 32; off > 0; off >>= 1) s += __shfl_down(s, off);
    if (lane == 0) wp[wv] = s;
    __syncthreads();
    if (tid == 0) out[0] = (wp[0] + wp[1] + wp[2] + wp[3]) / (float)M;
}

extern "C" void kernel_launch(void* const* d_in, const int* in_sizes, int n_in,
                              void* d_out, int out_size, void* d_ws, size_t ws_size,
                              hipStream_t stream) {
    const float* inp = (const float*)d_in[0];
    const int*   tgt = (const int*)d_in[1];
    float* out = (float*)d_out;
    float* row_loss = (float*)d_ws;      // 16 KiB of workspace

    fused_row_loss<<<M / 4, NT, 0, stream>>>(inp, tgt, row_loss);
    final_reduce<<<1, 256, 0, stream>>>(row_loss, out);
}

// Round 13
// 62.824 us; speedup vs baseline: 3.6802x; 1.1499x over previous
//
#include <hip/hip_runtime.h>

// inputs: [M=4096, N=16384] fp32 logits; targets: [M] int32; k = int(0.01*(N-1)) = 163
#define M        4096
#define N        16384
#define K_SEL    163
#define DELTA_W  5.0f
#define NT       256
#define CAPW     512           // per-row candidate cap (mean 372, sd 19; 7.4 sigma)
#define SCALE    4096.0f       // fixed-point for hard-negative sum (order-independent)
#define THRESH   2.0f          // E[count(x>=2)] = 373 per row; 11 sigma above K_SEL

typedef float vfloat4 __attribute__((ext_vector_type(4)));

// Order-preserving float<->uint32 key (ascending float <-> ascending key)
__device__ __forceinline__ unsigned f2key(float x) {
    unsigned u = __float_as_uint(x);
    return u ^ ((unsigned)((int)u >> 31) | 0x80000000u);
}
__device__ __forceinline__ float key2f(unsigned k) {
    unsigned u = k ^ (~(unsigned)((int)k >> 31) | 0x80000000u);
    return __uint_as_float(u);
}
__device__ __forceinline__ void wave_lgkm_wait() {
    asm volatile("s_waitcnt lgkmcnt(0)" ::: "memory");
}

// ---------- Fused kernel: wave-per-row stream -> direct LDS candidate list ----------
// Stream consume is branchless-pipelineable: ballot -> uniform running count (SGPR)
// -> mbcnt rank -> exec-masked ds_write of f2key(x). No atomics, no shfl chains.
__global__ __launch_bounds__(NT, 4) void fused_row_loss(
    const float* __restrict__ inp, const int* __restrict__ tgt,
    float* __restrict__ row_loss)
{
    __shared__ unsigned hist_all[4][256];   // wave-private 1 KiB
    __shared__ unsigned list_all[4][CAPW];  // wave-private 2 KiB (keys)
    const int lane = threadIdx.x & 63;
    const int wv   = threadIdx.x >> 6;
    const int row  = blockIdx.x * 4 + wv;
    unsigned* hist = hist_all[wv];
    unsigned* list = list_all[wv];
    const float* rp = inp + (size_t)row * N;
    const vfloat4* rp4 = reinterpret_cast<const vfloat4*>(rp);
    const int target = tgt[row];

    // target position decomposition: element t = it*256 + 4*lane + j
    const int it_t = target >> 8;
    const int l_t  = (target & 255) >> 2;
    const int j_t  = target & 3;

    // ---- Phase 1: stream row; push candidates straight to LDS list ----
    unsigned cnt = 0;                        // wave-uniform running candidate count
    #pragma unroll
    for (int it0 = 0; it0 < 64; it0 += 8) {
        vfloat4 v[8];                        // 8 loads in flight per batch
        #pragma unroll
        for (int u = 0; u < 8; ++u) v[u] = rp4[(it0 + u) * 64 + lane];
        #pragma unroll
        for (int u = 0; u < 8; ++u) {
            const int it = it0 + u;
            const bool tgt_here = (it == it_t) && (lane == l_t);
            #pragma unroll
            for (int j = 0; j < 4; ++j) {
                const bool pred = (v[u][j] >= THRESH) && !(tgt_here && j == j_t);
                const unsigned long long bal = __ballot(pred);
                if (pred) {
                    const unsigned rank = __builtin_amdgcn_mbcnt_hi(
                        (unsigned)(bal >> 32),
                        __builtin_amdgcn_mbcnt_lo((unsigned)bal, 0u));
                    const unsigned slot = cnt + rank;
                    if (slot < CAPW) list[slot] = f2key(v[u][j]);
                }
                cnt += (unsigned)__popcll(bal);   // SGPR add, stays uniform
            }
        }
    }
    const unsigned C = cnt;                  // exact count (overflow detectable)

    float loss = 0.0f;
    bool have = false;

    if (C >= K_SEL && C <= CAPW) {
        wave_lgkm_wait();                    // list writes visible to own wave

        // ---- keys live in LDS already: 8 reads, one wait ----
        unsigned keys[8];
        #pragma unroll
        for (int it = 0; it < 8; ++it) {
            const unsigned i = lane + it * 64u;
            keys[it] = (i < C) ? list[i] : 0u;     // pad with min-key
        }

        // ---- common-prefix detection: skip degenerate leading radix passes ----
        unsigned mn = 0xFFFFFFFFu, mx = 0u;
        #pragma unroll
        for (int it = 0; it < 8; ++it) {
            const unsigned i = lane + it * 64u;
            if (i < C) { mn = min(mn, keys[it]); mx = max(mx, keys[it]); }
        }
        #pragma unroll
        for (int off = 32; off > 0; off >>= 1) {
            mn = min(mn, (unsigned)__shfl_xor((int)mn, off));
            mx = max(mx, (unsigned)__shfl_xor((int)mx, off));
        }
        const unsigned diff = mn ^ mx;
        const int b0i = (diff == 0u) ? 3 : (__clz(diff) >> 3);   // first differing byte
        unsigned prefix = (b0i == 0) ? 0u : (mn >> (32 - 8 * b0i));
        unsigned kr = K_SEL;

        for (int pass = b0i; pass < 4; ++pass) {
            *reinterpret_cast<uint4*>(&hist[lane * 4]) = make_uint4(0, 0, 0, 0);
            wave_lgkm_wait();
            const int shift = 24 - 8 * pass;
            #pragma unroll
            for (int it = 0; it < 8; ++it) {
                unsigned k = keys[it];
                bool mm = (lane + it * 64u < C) &&
                          (pass == 0 || (k >> (shift + 8)) == prefix);
                if (mm) atomicAdd(&hist[(k >> shift) & 0xFFu], 1u);
            }
            wave_lgkm_wait();
            uint4 h = *reinterpret_cast<const uint4*>(&hist[lane * 4]);
            unsigned hb[4] = {h.x, h.y, h.z, h.w};
            unsigned s_local = hb[0] + hb[1] + hb[2] + hb[3];
            unsigned suf = s_local;                // suffix-scan over lanes
            #pragma unroll
            for (int off = 1; off < 64; off <<= 1) {
                unsigned o = __shfl_down(suf, off);
                suf += (lane + off < 64) ? o : 0u;
            }
            unsigned acc_above = suf - s_local;
            int foundc = -1; unsigned f_abv = 0;
            #pragma unroll
            for (int c = 3; c >= 0; --c) {
                unsigned S = acc_above + hb[c];
                if (acc_above < kr && S >= kr) { foundc = c; f_abv = acc_above; }
                acc_above = S;
            }
            bool win = (foundc >= 0);
            unsigned long long bal = __ballot(win);
            int wl = __ffsll((long long)bal) - 1;
            unsigned np = win ? ((prefix << 8) | (unsigned)(lane * 4 + foundc)) : 0u;
            unsigned nk = win ? (kr - f_abv) : 0u;
            prefix = __shfl(np, wl);
            kr     = __shfl(nk, wl);
        }
        const unsigned tkey = prefix, krem = kr;

        int facc = 0;                              // fixed-point, order-independent
        #pragma unroll
        for (int it = 0; it < 8; ++it) {
            unsigned k = keys[it];
            if ((lane + it * 64u) < C && k > tkey) {
                float ww = key2f(k) + 1.0f;
                facc += (int)(ww * ww * SCALE + 0.5f);
            }
        }
        #pragma unroll
        for (int off = 32; off > 0; off >>= 1) facc += __shfl_down(facc, off);
        if (lane == 0) {
            float tv    = key2f(tkey) + 1.0f;
            float total = (float)facc * (1.0f / SCALE) + (float)krem * tv * tv;
            float pd    = rp[target] - 1.0f;
            loss = DELTA_W * pd * pd + total * (1.0f / (float)K_SEL);
            have = true;
        }
    } else {
        // ---- fallback: exact full-row radix (never taken for Gaussian bench data) ----
        unsigned prefix = 0u, kr = K_SEL;
        for (int pass = 0; pass < 4; ++pass) {
            *reinterpret_cast<uint4*>(&hist[lane * 4]) = make_uint4(0, 0, 0, 0);
            wave_lgkm_wait();
            const int shift = 24 - 8 * pass;
            for (int it = 0; it < N / 64; ++it) {
                int i = lane + it * 64;
                unsigned k = f2key(rp[i]);
                if (i == target) k = 0u;
                bool mm = (pass == 0) || ((k >> (shift + 8)) == prefix);
                if (mm) atomicAdd(&hist[(k >> shift) & 0xFFu], 1u);
            }
            wave_lgkm_wait();
            uint4 h = *reinterpret_cast<const uint4*>(&hist[lane * 4]);
            unsigned hb[4] = {h.x, h.y, h.z, h.w};
            unsigned s_local = hb[0] + hb[1] + hb[2] + hb[3];
            unsigned suf = s_local;
            #pragma unroll
            for (int off = 1; off < 64; off <<= 1) {
                unsigned o = __shfl_down(suf, off);
                suf += (lane + off < 64) ? o : 0u;
            }
            unsigned acc_above = suf - s_local;
            int foundc = -1; unsigned f_abv = 0;
            #pragma unroll
            for (int c = 3; c >= 0; --c) {
                unsigned S = acc_above + hb[c];
                if (acc_above < kr && S >= kr) { foundc = c; f_abv = acc_above; }
                acc_above = S;
            }
            bool win = (foundc >= 0);
            unsigned long long bal = __ballot(win);
            int wl = __ffsll((long long)bal) - 1;
            unsigned np = win ? ((prefix << 8) | (unsigned)(lane * 4 + foundc)) : 0u;
            unsigned nk = win ? (kr - f_abv) : 0u;
            prefix = __shfl(np, wl);
            kr     = __shfl(nk, wl);
        }
        const unsigned tkey = prefix, krem = kr;

        int facc = 0;
        for (int it = 0; it < N / 64; ++it) {
            int i = lane + it * 64;
            unsigned k = f2key(rp[i]);
            if (i == target) k = 0u;
            if (k > tkey) { float ww = key2f(k) + 1.0f; facc += (int)(ww * ww * SCALE + 0.5f); }
        }
        #pragma unroll
        for (int off = 32; off > 0; off >>= 1) facc += __shfl_down(facc, off);
        if (lane == 0) {
            float tv    = key2f(tkey) + 1.0f;
            float total = (float)facc * (1.0f / SCALE) + (float)krem * tv * tv;
            float pd    = rp[target] - 1.0f;
            loss = DELTA_W * pd * pd + total * (1.0f / (float)K_SEL);
            have = true;
        }
    }

    if (have) row_loss[row] = loss;
}

__global__ __launch_bounds__(256) void final_reduce(
    const float* __restrict__ rl, float* __restrict__ out)
{
    int tid = threadIdx.x;
    float s = 0.0f;
    for (int i = tid; i < M; i += 256) s += rl[i];   // fixed order -> deterministic
    __shared__ float wp[4];
    int lane = tid & 63, wv = tid >> 6;
    #pragma unroll
    for (int off = 32; off > 0; off >>= 1) s += __shfl_down(s, off);
    if (lane == 0) wp[wv] = s;
    __syncthreads();
    if (tid == 0) out[0] = (wp[0] + wp[1] + wp[2] + wp[3]) / (float)M;
}

extern "C" void kernel_launch(void* const* d_in, const int* in_sizes, int n_in,
                              void* d_out, int out_size, void* d_ws, size_t ws_size,
                              hipStream_t stream) {
    const float* inp = (const float*)d_in[0];
    const int*   tgt = (const int*)d_in[1];
    float* out = (float*)d_out;
    float* row_loss = (float*)d_ws;      // 16 KiB of workspace

    fused_row_loss<<<M / 4, NT, 0, stream>>>(inp, tgt, row_loss);
    final_reduce<<<1, 256, 0, stream>>>(row_loss, out);
}